// Round 1
// baseline (251.298 us; speedup 1.0000x reference)
//
#include <hip/hip_runtime.h>
#include <math.h>

// Problem constants (match reference)
#define NNODES 50000
#define NEDGES 800000
#define INF 128
#define OUTF 128
#define HEADS 2
#define NEG_SLOPE 0.2f

// Padded-bin CSR: degree ~ Poisson(16); CAP=32 overflows on ~1e-4 of nodes;
// overflow edges go to a small exact-path list.
#define CAP 32
#define OVFCAP 32768

__device__ __forceinline__ unsigned short f2bf(float f) {
    unsigned u = __float_as_uint(f);
    unsigned r = (u + 0x7FFFu + ((u >> 16) & 1u)) >> 16;   // RNE
    return (unsigned short)r;
}
__device__ __forceinline__ float bf2f(unsigned short b) {
    return __uint_as_float((unsigned)b << 16);
}

typedef __attribute__((ext_vector_type(8))) short frag_ab;   // 8 bf16 (4 VGPRs)
typedef __attribute__((ext_vector_type(4))) float frag_cd;   // 4 fp32 acc

// ---------- K0: init scratch + one-time param prep ----------
// blocks [0, cblk): zero cursor/ovfcnt
// block  cblk     : wfold[vq][128]  vq=0,1: attn_l-folded W per head; 2,3: attn_r
// blocks cblk+1..cblk+8 : Wb = bf16(W)  (32768 elems)
__global__ void init_kernel(int* cursor, int* ovfcnt,
                            const float* __restrict__ W,
                            const float* __restrict__ attn_l,
                            const float* __restrict__ attn_r,
                            unsigned short* __restrict__ Wb,
                            float* __restrict__ wfold, int N) {
    const int b = blockIdx.x, t = threadIdx.x;
    const int cblk = (N + 255) >> 8;
    if (b < cblk) {
        int i = b * 256 + t;
        if (i < N) cursor[i] = 0;
        if (i == 0) *ovfcnt = 0;
        return;
    }
    if (b == cblk) {
        // el[n,h] = feat[n]·wfold[h], er[n,h] = feat[n]·wfold[2+h]
        int h = t >> 7, f = t & 127;
        float sl = 0.f, sr = 0.f;
        for (int o = 0; o < 128; ++o) {
            float wv = W[(size_t)(h * 128 + o) * 128 + f];
            sl = fmaf(attn_l[h * 128 + o], wv, sl);
            sr = fmaf(attn_r[h * 128 + o], wv, sr);
        }
        wfold[h * 128 + f] = sl;
        wfold[(2 + h) * 128 + f] = sr;
        return;
    }
    int base = (b - cblk - 1) * 4096 + t * 16;
#pragma unroll
    for (int q = 0; q < 4; ++q) {
        float4 g = *(const float4*)(W + base + q * 4);
        ushort4 v; v.x = f2bf(g.x); v.y = f2bf(g.y); v.z = f2bf(g.z); v.w = f2bf(g.w);
        *(ushort4*)(Wb + base + q * 4) = v;
    }
}

// ---------- K1: MFMA gemm, no LDS / no barriers ----------
// 4 waves/block, wave w owns node rows n0+w*16..+15. A frags: direct fp32 load
// from feat + in-register bf16 convert (each element converted once chip-wide).
// B frags: direct 16B loads from pre-converted Wb (L1/L2-hot, 64 KB).
// el/er computed as exact fp32 dots feat·wfold on the A registers.
// C/D layout (verified m89/m91): col=lane&15, row=(lane>>4)*4+reg.
__global__ __launch_bounds__(256) void gemm_mfma(const float* __restrict__ feat,
                                                 const unsigned short* __restrict__ Wb,
                                                 const float* __restrict__ wfold,
                                                 unsigned short* __restrict__ ftb,
                                                 float* __restrict__ el,
                                                 float* __restrict__ er,
                                                 int N) {
    const int t = threadIdx.x;
    const int w = t >> 6, lane = t & 63;
    const int m16 = lane & 15, quad = lane >> 4;
    const int n0 = blockIdx.x * 64;
    const int r = n0 + w * 16 + m16;      // this lane's A row
    const bool valid = r < N;

    frag_ab af[4];
    float pd[4] = {0.f, 0.f, 0.f, 0.f};   // wl0, wl1, wr0, wr1 partial dots
#pragma unroll
    for (int kc = 0; kc < 4; ++kc) {
        const int cc = kc * 32 + quad * 8;
        float4 g0 = make_float4(0.f, 0.f, 0.f, 0.f), g1 = g0;
        if (valid) {
            g0 = *(const float4*)(feat + (size_t)r * INF + cc);
            g1 = *(const float4*)(feat + (size_t)r * INF + cc + 4);
        }
        frag_ab a;
        a[0] = (short)f2bf(g0.x); a[1] = (short)f2bf(g0.y);
        a[2] = (short)f2bf(g0.z); a[3] = (short)f2bf(g0.w);
        a[4] = (short)f2bf(g1.x); a[5] = (short)f2bf(g1.y);
        a[6] = (short)f2bf(g1.z); a[7] = (short)f2bf(g1.w);
        af[kc] = a;
#pragma unroll
        for (int vq = 0; vq < 4; ++vq) {
            float4 w0 = *(const float4*)(wfold + vq * 128 + cc);
            float4 w1 = *(const float4*)(wfold + vq * 128 + cc + 4);
            pd[vq] += g0.x * w0.x + g0.y * w0.y + g0.z * w0.z + g0.w * w0.w
                    + g1.x * w1.x + g1.y * w1.y + g1.z * w1.z + g1.w * w1.w;
        }
    }
    // lane's 32 cols are 1/4 of the row; reduce across the 4 quads (xor 16,32)
#pragma unroll
    for (int m = 16; m < 64; m <<= 1)
#pragma unroll
        for (int vq = 0; vq < 4; ++vq) pd[vq] += __shfl_xor(pd[vq], m, 64);
    if (valid && quad == 0) {
        *(float2*)(el + (size_t)r * 2) = make_float2(pd[0], pd[1]);
        *(float2*)(er + (size_t)r * 2) = make_float2(pd[2], pd[3]);
    }

#pragma unroll
    for (int jt = 0; jt < 4; ++jt) {
        frag_cd acc[4];
#pragma unroll
        for (int nt = 0; nt < 4; ++nt) acc[nt] = frag_cd{0.f, 0.f, 0.f, 0.f};
#pragma unroll
        for (int kc = 0; kc < 4; ++kc) {
#pragma unroll
            for (int nt = 0; nt < 4; ++nt) {
                frag_ab bf = *(const frag_ab*)(Wb + (size_t)(jt * 64 + nt * 16 + m16) * INF
                                               + kc * 32 + quad * 8);
                acc[nt] = __builtin_amdgcn_mfma_f32_16x16x32_bf16(af[kc], bf, acc[nt], 0, 0, 0);
            }
        }
#pragma unroll
        for (int nt = 0; nt < 4; ++nt) {
            const int gj = jt * 64 + nt * 16 + m16;       // global j (= h*128+o flat)
#pragma unroll
            for (int reg = 0; reg < 4; ++reg) {
                int gm = n0 + w * 16 + quad * 4 + reg;
                if (gm < N) ftb[(size_t)gm * 256 + gj] = f2bf(acc[nt][reg]);
            }
        }
    }
}

// ---------- K2: fused edge logits + leaky_relu + exp + padded-bin scatter ----------
// No segment-max (softmax shift-invariant; logits O(10), exp safe in fp32).
__global__ void edge_fused(const float* __restrict__ el, const float* __restrict__ er,
                           const float* __restrict__ e_w, const int* __restrict__ src,
                           const int* __restrict__ dst, const float* __restrict__ attn_ew,
                           int* __restrict__ cursor, int* __restrict__ ovfcnt,
                           uint2* __restrict__ edata, float4* __restrict__ ovf,
                           int E) {
    int e = blockIdx.x * 256 + threadIdx.x;
    if (e >= E) return;
    int s = src[e], d = dst[e];
    float2 ew2 = *(const float2*)(e_w + (size_t)e * 2);
    float2 elv = *(const float2*)(el + (size_t)s * 2);
    float2 erv = *(const float2*)(er + (size_t)d * 2);
    float v0 = elv.x + erv.x + ew2.x * attn_ew[0] + ew2.y * attn_ew[1];
    float v1 = elv.y + erv.y + ew2.x * attn_ew[2] + ew2.y * attn_ew[3];
    v0 = v0 >= 0.f ? v0 : NEG_SLOPE * v0;
    v1 = v1 >= 0.f ? v1 : NEG_SLOPE * v1;
    float ee0 = __expf(v0);
    float ee1 = __expf(v1);
    int pos = atomicAdd(cursor + d, 1);
    if (pos < CAP) {
        unsigned pk = ((unsigned)f2bf(ee1) << 16) | (unsigned)f2bf(ee0);
        edata[(size_t)d * CAP + pos] = make_uint2((unsigned)s, pk);
    } else {
        int o = atomicAdd(ovfcnt, 1);
        if (o < OVFCAP)
            ovf[o] = make_float4(__int_as_float(d), __int_as_float(s), ee0, ee1);
    }
}

// ---------- K3: wave-per-node gather-aggregate + normalize + residual + elu ----------
// Whole 32-record bin prefetched once (one uint2/lane); per-edge record comes
// from readlane (wave-uniform index) so src lands in an SGPR -> scalar gather
// base, no per-iteration edata load on the critical path.
__global__ __launch_bounds__(256) void aggregate(const unsigned short* __restrict__ ftb,
                                                 const float* __restrict__ feat,
                                                 const uint2* __restrict__ edata,
                                                 const int* __restrict__ cursor,
                                                 const int* __restrict__ ovfcnt,
                                                 const float4* __restrict__ ovf,
                                                 float* __restrict__ out, int N) {
    const int t = threadIdx.x;
    const int w = t >> 6, l = t & 63;
    const int n = blockIdx.x * 4 + w;
    if (n >= N) return;
    const int c0 = 4 * l;            // this lane's 4 cols (0..252)
    const int h = l >> 5;            // lane's head
    const int cnt = cursor[n];
    const int cmain = cnt < CAP ? cnt : CAP;
    const uint2* eb = edata + (size_t)n * CAP;
    const uint2 myrec = eb[l & 31];  // prefetch whole bin; recs >= cmain unused

    float4 acc = make_float4(0.f, 0.f, 0.f, 0.f);
    float dn = 0.f;
#pragma unroll 4
    for (int i = 0; i < cmain; ++i) {
        unsigned sx = (unsigned)__builtin_amdgcn_readlane((int)myrec.x, i);
        unsigned pk = (unsigned)__builtin_amdgcn_readlane((int)myrec.y, i);
        float a = bf2f((unsigned short)(h ? (pk >> 16) : (pk & 0xFFFFu)));
        const ushort4 v = *(const ushort4*)(ftb + (size_t)sx * 256 + c0);
        dn += a;
        acc.x = fmaf(a, bf2f(v.x), acc.x);
        acc.y = fmaf(a, bf2f(v.y), acc.y);
        acc.z = fmaf(a, bf2f(v.z), acc.z);
        acc.w = fmaf(a, bf2f(v.w), acc.w);
    }
    if (cnt > CAP) {   // exact overflow path (rare)
        int no = *ovfcnt; if (no > OVFCAP) no = OVFCAP;
        for (int i = 0; i < no; ++i) {
            float4 ov = ovf[i];
            if (__float_as_int(ov.x) == n) {
                int s = __float_as_int(ov.y);
                float a = h ? ov.w : ov.z;
                dn += a;
                const ushort4 v = *(const ushort4*)(ftb + (size_t)s * 256 + c0);
                acc.x = fmaf(a, bf2f(v.x), acc.x);
                acc.y = fmaf(a, bf2f(v.y), acc.y);
                acc.z = fmaf(a, bf2f(v.z), acc.z);
                acc.w = fmaf(a, bf2f(v.w), acc.w);
            }
        }
    }
    float inv = dn > 0.f ? 1.0f / dn : 0.f;
    float4 f4 = *(const float4*)(feat + (size_t)n * INF + (c0 & 127));
    float4 r;
    r.x = acc.x * inv + f4.x;
    r.y = acc.y * inv + f4.y;
    r.z = acc.z * inv + f4.z;
    r.w = acc.w * inv + f4.w;
    r.x = r.x > 0.f ? r.x : expm1f(r.x);
    r.y = r.y > 0.f ? r.y : expm1f(r.y);
    r.z = r.z > 0.f ? r.z : expm1f(r.z);
    r.w = r.w > 0.f ? r.w : expm1f(r.w);
    *(float4*)(out + (size_t)n * 256 + c0) = r;
}

extern "C" void kernel_launch(void* const* d_in, const int* in_sizes, int n_in,
                              void* d_out, int out_size, void* d_ws, size_t ws_size,
                              hipStream_t stream) {
    const float* feat    = (const float*)d_in[0];
    const float* e_w     = (const float*)d_in[1];
    const int*   src     = (const int*)d_in[2];
    const int*   dst     = (const int*)d_in[3];
    const float* W       = (const float*)d_in[4];
    const float* attn_l  = (const float*)d_in[5];
    const float* attn_r  = (const float*)d_in[6];
    const float* attn_ew = (const float*)d_in[7];
    float* out = (float*)d_out;

    const int N = in_sizes[0] / INF;   // 50000
    const int E = in_sizes[2];         // 800000

    // workspace carve-up (all offsets 16B-aligned for these sizes)
    unsigned short* ftb = (unsigned short*)d_ws;                 // N*256 bf16   (25.6 MB)
    uint2*  edata  = (uint2*)(ftb + (size_t)N * 256);            // N*CAP        (12.8 MB)
    float*  el     = (float*)(edata + (size_t)N * CAP);          // N*2          (0.4 MB)
    float*  er     = el + (size_t)N * 2;                         // N*2          (0.4 MB)
    float*  wfold  = er + (size_t)N * 2;                         // 4*128 f      (2 KB)
    unsigned short* Wb = (unsigned short*)(wfold + 512);         // 256*128 bf16 (64 KB)
    float4* ovf    = (float4*)(Wb + 32768);                      // OVFCAP       (0.5 MB)
    int*    cursor = (int*)(ovf + OVFCAP);                       // N
    int*    ovfcnt = cursor + N;                                 // 1

    const int cblk = (N + 255) / 256;
    init_kernel<<<cblk + 9, 256, 0, stream>>>(cursor, ovfcnt, W, attn_l, attn_r, Wb, wfold, N);

    gemm_mfma<<<(N + 63) / 64, 256, 0, stream>>>(feat, Wb, wfold, ftb, el, er, N);

    edge_fused<<<(E + 255) / 256, 256, 0, stream>>>(el, er, e_w, src, dst, attn_ew,
                                                    cursor, ovfcnt, edata, ovf, E);

    aggregate<<<(N + 3) / 4, 256, 0, stream>>>(ftb, feat, edata, cursor, ovfcnt, ovf, out, N);
}